// Round 4
// baseline (525.448 us; speedup 1.0000x reference)
//
#include <hip/hip_runtime.h>
#include <hip/hip_fp16.h>

#define N_NODES 100000
#define N_EDGES 1600000
#define CH 128
#define OCH 64
#define NB_SCAN 391  // ceil(100000/256)

typedef _Float16 half8 __attribute__((ext_vector_type(8)));
typedef float f32x4 __attribute__((ext_vector_type(4)));

__device__ __forceinline__ ushort f2h(float f) {
    _Float16 h = (_Float16)f;
    return *(ushort*)&h;
}

__device__ __forceinline__ uint pkadd(uint a, uint b) {
    __half2 r = __hadd2(*(__half2*)&a, *(__half2*)&b);
    return *(uint*)&r;
}

// XOR-swizzled f16 offset inside a [rows][128] f16 tile.
__device__ __forceinline__ int swz(int row, int k) {
    return row * 128 + ((((k >> 3) ^ (row & 15)) << 3) | (k & 7));
}

// ---------------- CSR build ----------------

__global__ void k_count(const int4* __restrict__ dst4, int* __restrict__ cnt) {
    int i = blockIdx.x * blockDim.x + threadIdx.x;
    if (i < N_EDGES / 4) {
        int4 d = dst4[i];
        atomicAdd(&cnt[d.x], 1);
        atomicAdd(&cnt[d.y], 1);
        atomicAdd(&cnt[d.z], 1);
        atomicAdd(&cnt[d.w], 1);
    }
}

// exclusive scan pass 1 (+ fused dis = rsqrt(deg))
__global__ void k_scan1(const int* __restrict__ cnt, int* __restrict__ rowptr,
                        int* __restrict__ bsum, float* __restrict__ dis) {
    __shared__ int tmp[256];
    int i = blockIdx.x * 256 + threadIdx.x;
    int v = (i < N_NODES) ? cnt[i] : 0;
    if (i < N_NODES) dis[i] = rsqrtf((float)(v + 1));  // +1 self-loop
    tmp[threadIdx.x] = v;
    __syncthreads();
    for (int off = 1; off < 256; off <<= 1) {
        int t = (threadIdx.x >= off) ? tmp[threadIdx.x - off] : 0;
        __syncthreads();
        tmp[threadIdx.x] += t;
        __syncthreads();
    }
    if (i < N_NODES) rowptr[i] = tmp[threadIdx.x] - v;  // block-local exclusive
    if (threadIdx.x == 255) bsum[blockIdx.x] = tmp[255];
}

__global__ void k_scan2(int* __restrict__ bsum) {
    __shared__ int tmp[512];
    int v = (threadIdx.x < NB_SCAN) ? bsum[threadIdx.x] : 0;
    tmp[threadIdx.x] = v;
    __syncthreads();
    for (int off = 1; off < 512; off <<= 1) {
        int t = (threadIdx.x >= off) ? tmp[threadIdx.x - off] : 0;
        __syncthreads();
        tmp[threadIdx.x] += t;
        __syncthreads();
    }
    if (threadIdx.x < NB_SCAN) bsum[threadIdx.x] = tmp[threadIdx.x] - v;
}

// scatter with bsum folded in; bare src index, nontemporal 4B store
__global__ void k_scatter(const int* __restrict__ src, const int* __restrict__ dst,
                          const int* __restrict__ rowptr, const int* __restrict__ bsum,
                          int* __restrict__ fill, int* __restrict__ esrc) {
    int e = blockIdx.x * blockDim.x + threadIdx.x;
    if (e >= N_EDGES) return;
    int s = src[e], d = dst[e];
    int pos = rowptr[d] + bsum[d >> 8] + atomicAdd(&fill[d], 1);
    __builtin_nontemporal_store(s, &esrc[pos]);
}

// ---------------- weight prep (all three, one launch) ----------------

__global__ void k_prepW(const float* __restrict__ W1, const float* __restrict__ W2,
                        const float* __restrict__ Wo, ushort* __restrict__ W1s,
                        ushort* __restrict__ W2s, ushort* __restrict__ WoTs) {
    int i = blockIdx.x * blockDim.x + threadIdx.x;  // 0..40959
    if (i < 16384) {
        int k = i >> 7, n = i & 127;
        W1s[swz(n, k)] = f2h(W1[i]);
    } else if (i < 32768) {
        int j = i - 16384, k = j >> 7, n = j & 127;
        W2s[swz(n, k)] = f2h(W2[j]);
    } else if (i < 40960) {
        int j = i - 32768, k = j >> 6, n = j & 63;
        WoTs[swz(n, k)] = f2h(Wo[j]);
    }
}

// ---------------- MFMA GEMM: out_f16[r] = dis[r] * (A[r] @ W) ----------------

template <typename IT>
__global__ __launch_bounds__(256) void k_gemm_mfma(const IT* __restrict__ A,
                                                   const ushort* __restrict__ Ws,
                                                   const float* __restrict__ dis,
                                                   ushort* __restrict__ out) {
    __shared__ ushort sB[128 * 128];
    __shared__ ushort sA[64 * 128];
    const int tid = threadIdx.x;
    const int row0 = blockIdx.x * 64;

    for (int i = tid; i < 2048; i += 256)
        ((float4*)sB)[i] = ((const float4*)Ws)[i];

    for (int i = tid; i < 2048; i += 256) {
        int m = i >> 5, u = i & 31, k4 = u << 2;
        int r = row0 + m;
        ushort4 pk = make_ushort4(0, 0, 0, 0);
        if (r < N_NODES) {
            if constexpr (sizeof(IT) == 4) {
                float4 a = ((const float4*)A)[r * 32 + u];
                pk = make_ushort4(f2h(a.x), f2h(a.y), f2h(a.z), f2h(a.w));
            } else {
                pk = ((const ushort4*)A)[r * 32 + u];
            }
        }
        *(ushort4*)&sA[swz(m, k4)] = pk;
    }
    __syncthreads();

    const int lane = tid & 63, wv = tid >> 6;
    const int mrow = lane & 15, quad = lane >> 4;
    f32x4 acc[8] = {};
#pragma unroll
    for (int kc = 0; kc < 4; ++kc) {
        int g = kc * 4 + quad;
        half8 a = *(const half8*)&sA[(wv * 16 + mrow) * 128 + ((g ^ mrow) << 3)];
#pragma unroll
        for (int nt = 0; nt < 8; ++nt) {
            half8 b = *(const half8*)&sB[(nt * 16 + mrow) * 128 + ((g ^ mrow) << 3)];
            acc[nt] = __builtin_amdgcn_mfma_f32_16x16x32_f16(a, b, acc[nt], 0, 0, 0);
        }
    }

    const int rbase = row0 + wv * 16 + quad * 4;
    float ds[4];
#pragma unroll
    for (int rg = 0; rg < 4; ++rg)
        ds[rg] = (rbase + rg < N_NODES) ? dis[rbase + rg] : 0.f;
#pragma unroll
    for (int nt = 0; nt < 8; ++nt) {
#pragma unroll
        for (int rg = 0; rg < 4; ++rg) {
            int r = rbase + rg;
            if (r < N_NODES) out[r * 128 + nt * 16 + mrow] = f2h(acc[nt][rg] * ds[rg]);
        }
    }
}

// ---------------- CSR aggregation ----------------
// out[v] = relu(dis[v] * (sum_e h'[src_e] + h'[v]) + bias), fp16 pk accumulate.
// One wave per node; half-wave per edge (lane holds 4 channels, 8B loads).

__global__ __launch_bounds__(256) void k_agg(const int* __restrict__ rowptr,
                                             const int* __restrict__ bsum,
                                             const int* __restrict__ esrc,
                                             const ushort* __restrict__ h,
                                             const float* __restrict__ dis,
                                             const float* __restrict__ bias,
                                             ushort* __restrict__ out) {
    const int v = blockIdx.x * 4 + (threadIdx.x >> 6);
    const int lane = threadIdx.x & 63, half = lane >> 5, l = lane & 31;
    const uint2* h4 = (const uint2*)h;

    int e0 = rowptr[v] + bsum[v >> 8];
    int e1 = (v == N_NODES - 1) ? N_EDGES : rowptr[v + 1] + bsum[(v + 1) >> 8];
    int n = e1 - e0;
    const int* ep = esrc + e0;

    uint2 acc = make_uint2(0, 0);
    int i = half;
    for (; i + 3 < n; i += 4) {  // this half handles i, i+2 (2 rows in flight)
        int s0 = ep[i], s1 = ep[i + 2];
        uint2 t0 = h4[s0 * 32 + l];
        uint2 t1 = h4[s1 * 32 + l];
        acc.x = pkadd(acc.x, t0.x); acc.y = pkadd(acc.y, t0.y);
        acc.x = pkadd(acc.x, t1.x); acc.y = pkadd(acc.y, t1.y);
    }
    for (; i < n; i += 2) {
        int s0 = ep[i];
        uint2 t0 = h4[s0 * 32 + l];
        acc.x = pkadd(acc.x, t0.x); acc.y = pkadd(acc.y, t0.y);
    }
    // combine halves
    acc.x = pkadd(acc.x, (uint)__shfl_xor((int)acc.x, 32));
    acc.y = pkadd(acc.y, (uint)__shfl_xor((int)acc.y, 32));

    if (half == 0) {
        uint2 hv = h4[v * 32 + l];  // self-loop term h'[v]
        acc.x = pkadd(acc.x, hv.x);
        acc.y = pkadd(acc.y, hv.y);
        float s = dis[v];
        float2 a0 = __half22float2(*(__half2*)&acc.x);
        float2 a1 = __half22float2(*(__half2*)&acc.y);
        float4 bv = *(const float4*)&bias[l * 4];
        a0.x = fmaxf(a0.x * s + bv.x, 0.f);
        a0.y = fmaxf(a0.y * s + bv.y, 0.f);
        a1.x = fmaxf(a1.x * s + bv.z, 0.f);
        a1.y = fmaxf(a1.y * s + bv.w, 0.f);
        __half2 o0 = __float22half2_rn(make_float2(a0.x, a0.y));
        __half2 o1 = __float22half2_rn(make_float2(a1.x, a1.y));
        ((uint2*)out)[v * 32 + l] = make_uint2(*(uint*)&o0, *(uint*)&o1);
    }
}

// ---------------- final MFMA: out_f32[N][64] = (x1+x2)@Wo + bo ----------------

__global__ __launch_bounds__(256) void k_final_mfma(const ushort* __restrict__ x1,
                                                    const ushort* __restrict__ x2,
                                                    const ushort* __restrict__ Ws,
                                                    const float* __restrict__ bo,
                                                    float* __restrict__ out) {
    __shared__ ushort sB[64 * 128];
    __shared__ ushort sA[64 * 128];
    const int tid = threadIdx.x;
    const int row0 = blockIdx.x * 64;

    for (int i = tid; i < 1024; i += 256)
        ((float4*)sB)[i] = ((const float4*)Ws)[i];

    for (int i = tid; i < 2048; i += 256) {
        int m = i >> 5, u = i & 31, k4 = u << 2;
        int r = row0 + m;
        uint2 pk = make_uint2(0, 0);
        if (r < N_NODES) {
            uint2 ua = ((const uint2*)x1)[r * 32 + u];
            uint2 ub = ((const uint2*)x2)[r * 32 + u];
            __half2 s0 = __hadd2(*(__half2*)&ua.x, *(__half2*)&ub.x);
            __half2 s1 = __hadd2(*(__half2*)&ua.y, *(__half2*)&ub.y);
            pk = make_uint2(*(uint*)&s0, *(uint*)&s1);
        }
        *(uint2*)&sA[swz(m, k4)] = pk;
    }
    __syncthreads();

    const int lane = tid & 63, wv = tid >> 6;
    const int mrow = lane & 15, quad = lane >> 4;
    f32x4 acc[4] = {};
#pragma unroll
    for (int kc = 0; kc < 4; ++kc) {
        int g = kc * 4 + quad;
        half8 a = *(const half8*)&sA[(wv * 16 + mrow) * 128 + ((g ^ mrow) << 3)];
#pragma unroll
        for (int nt = 0; nt < 4; ++nt) {
            half8 b = *(const half8*)&sB[(nt * 16 + mrow) * 128 + ((g ^ mrow) << 3)];
            acc[nt] = __builtin_amdgcn_mfma_f32_16x16x32_f16(a, b, acc[nt], 0, 0, 0);
        }
    }

    const int rbase = row0 + wv * 16 + quad * 4;
#pragma unroll
    for (int nt = 0; nt < 4; ++nt) {
        float bb = bo[nt * 16 + mrow];
#pragma unroll
        for (int rg = 0; rg < 4; ++rg) {
            int r = rbase + rg;
            if (r < N_NODES) out[(size_t)r * 64 + nt * 16 + mrow] = acc[nt][rg] + bb;
        }
    }
}

// ---------------- launch ----------------

extern "C" void kernel_launch(void* const* d_in, const int* in_sizes, int n_in,
                              void* d_out, int out_size, void* d_ws, size_t ws_size,
                              hipStream_t stream) {
    const float* x  = (const float*)d_in[0];
    const int*   ei = (const int*)d_in[1];
    const int*   src = ei;
    const int*   dst = ei + N_EDGES;
    const float* W1 = (const float*)d_in[2];
    const float* b1 = (const float*)d_in[3];
    const float* W2 = (const float*)d_in[4];
    const float* b2 = (const float*)d_in[5];
    const float* Wo = (const float*)d_in[6];
    const float* bo = (const float*)d_in[7];
    float* out = (float*)d_out;

    char* ws = (char*)d_ws;
    int*    cnt    = (int*)ws;            ws += 400000;
    int*    fill   = (int*)ws;            ws += 400000;  // adjacent to cnt: one memset
    int*    rowptr = (int*)ws;            ws += 400064;
    int*    bsum   = (int*)ws;            ws += 2048;
    float*  dis    = (float*)ws;          ws += 400000;
    int*    esrc   = (int*)ws;            ws += (size_t)N_EDGES * 4;
    ushort* W1s    = (ushort*)ws;         ws += 32768;
    ushort* W2s    = (ushort*)ws;         ws += 32768;
    ushort* WoTs   = (ushort*)ws;         ws += 16384;
    ushort* h      = (ushort*)ws;         ws += (size_t)N_NODES * CH * 2;
    ushort* x1     = (ushort*)ws;         ws += (size_t)N_NODES * CH * 2;
    ushort* x2     = (ushort*)ws;

    const int B = 256;
    const int gE = (N_EDGES + B - 1) / B;
    const int gG = (N_NODES + 63) / 64;  // 1563

    // CSR build + weight prep
    hipMemsetAsync(cnt, 0, 800000, stream);  // cnt + fill
    k_count<<<(N_EDGES / 4 + B - 1) / B, B, 0, stream>>>((const int4*)dst, cnt);
    k_scan1<<<NB_SCAN, 256, 0, stream>>>(cnt, rowptr, bsum, dis);
    k_scan2<<<1, 512, 0, stream>>>(bsum);
    k_scatter<<<gE, B, 0, stream>>>(src, dst, rowptr, bsum, fill, esrc);
    k_prepW<<<160, B, 0, stream>>>(W1, W2, Wo, W1s, W2s, WoTs);

    // layer 1
    k_gemm_mfma<float><<<gG, B, 0, stream>>>(x, W1s, dis, h);
    k_agg<<<N_NODES / 4, B, 0, stream>>>(rowptr, bsum, esrc, h, dis, b1, x1);

    // layer 2
    k_gemm_mfma<ushort><<<gG, B, 0, stream>>>(x1, W2s, dis, h);
    k_agg<<<N_NODES / 4, B, 0, stream>>>(rowptr, bsum, esrc, h, dis, b2, x2);

    // output projection
    k_final_mfma<<<gG, B, 0, stream>>>(x1, x2, WoTs, bo, out);
}

// Round 5
// 504.665 us; speedup vs baseline: 1.0412x; 1.0412x over previous
//
#include <hip/hip_runtime.h>
#include <hip/hip_fp16.h>

#define N_NODES 100000
#define N_EDGES 1600000
#define CH 128
#define OCH 64
#define NB_SCAN 391  // ceil(100000/256)

typedef _Float16 half8 __attribute__((ext_vector_type(8)));
typedef float f32x4 __attribute__((ext_vector_type(4)));

__device__ __forceinline__ ushort f2h(float f) {
    _Float16 h = (_Float16)f;
    return *(ushort*)&h;
}

__device__ __forceinline__ uint pkadd(uint a, uint b) {
    __half2 r = __hadd2(*(__half2*)&a, *(__half2*)&b);
    return *(uint*)&r;
}

// XOR-swizzled f16 offset inside a [rows][128] f16 tile.
__device__ __forceinline__ int swz(int row, int k) {
    return row * 128 + ((((k >> 3) ^ (row & 15)) << 3) | (k & 7));
}

// ---------------- CSR build ----------------

__global__ void k_count(const int4* __restrict__ dst4, int* __restrict__ cnt) {
    int i = blockIdx.x * blockDim.x + threadIdx.x;
    if (i < N_EDGES / 4) {
        int4 d = dst4[i];
        atomicAdd(&cnt[d.x], 1);
        atomicAdd(&cnt[d.y], 1);
        atomicAdd(&cnt[d.z], 1);
        atomicAdd(&cnt[d.w], 1);
    }
}

// exclusive scan pass 1 (+ fused dis = rsqrt(deg))
__global__ void k_scan1(const int* __restrict__ cnt, int* __restrict__ rowptr,
                        int* __restrict__ bsum, float* __restrict__ dis) {
    __shared__ int tmp[256];
    int i = blockIdx.x * 256 + threadIdx.x;
    int v = (i < N_NODES) ? cnt[i] : 0;
    if (i < N_NODES) dis[i] = rsqrtf((float)(v + 1));  // +1 self-loop
    tmp[threadIdx.x] = v;
    __syncthreads();
    for (int off = 1; off < 256; off <<= 1) {
        int t = (threadIdx.x >= off) ? tmp[threadIdx.x - off] : 0;
        __syncthreads();
        tmp[threadIdx.x] += t;
        __syncthreads();
    }
    if (i < N_NODES) rowptr[i] = tmp[threadIdx.x] - v;  // block-local exclusive
    if (threadIdx.x == 255) bsum[blockIdx.x] = tmp[255];
}

__global__ void k_scan2(int* __restrict__ bsum) {
    __shared__ int tmp[512];
    int v = (threadIdx.x < NB_SCAN) ? bsum[threadIdx.x] : 0;
    tmp[threadIdx.x] = v;
    __syncthreads();
    for (int off = 1; off < 512; off <<= 1) {
        int t = (threadIdx.x >= off) ? tmp[threadIdx.x - off] : 0;
        __syncthreads();
        tmp[threadIdx.x] += t;
        __syncthreads();
    }
    if (threadIdx.x < NB_SCAN) bsum[threadIdx.x] = tmp[threadIdx.x] - v;
}

// materialize global rowptr into `next` (scatter's atomic counter)
__global__ void k_next(const int* __restrict__ rowptr, const int* __restrict__ bsum,
                       int* __restrict__ next) {
    int i = blockIdx.x * 256 + threadIdx.x;
    if (i < N_NODES) next[i] = rowptr[i] + bsum[i >> 8];
}

// single atomic returns the slot directly; plain (L2-absorbed) store
__global__ void k_scatter(const int* __restrict__ src, const int* __restrict__ dst,
                          int* __restrict__ next, int* __restrict__ esrc) {
    int e = blockIdx.x * blockDim.x + threadIdx.x;
    if (e >= N_EDGES) return;
    int s = src[e], d = dst[e];
    int pos = atomicAdd(&next[d], 1);
    esrc[pos] = s;
}
// post-scatter invariant: next[v] == global rowptr[v+1]

// ---------------- weight prep (all three, one launch) ----------------

__global__ void k_prepW(const float* __restrict__ W1, const float* __restrict__ W2,
                        const float* __restrict__ Wo, ushort* __restrict__ W1s,
                        ushort* __restrict__ W2s, ushort* __restrict__ WoTs) {
    int i = blockIdx.x * blockDim.x + threadIdx.x;  // 0..40959
    if (i < 16384) {
        int k = i >> 7, n = i & 127;
        W1s[swz(n, k)] = f2h(W1[i]);
    } else if (i < 32768) {
        int j = i - 16384, k = j >> 7, n = j & 127;
        W2s[swz(n, k)] = f2h(W2[j]);
    } else if (i < 40960) {
        int j = i - 32768, k = j >> 6, n = j & 63;
        WoTs[swz(n, k)] = f2h(Wo[j]);
    }
}

// ---------------- MFMA GEMM: out_f16[r] = dis[r] * (A[r] @ W) ----------------

template <typename IT>
__global__ __launch_bounds__(256) void k_gemm_mfma(const IT* __restrict__ A,
                                                   const ushort* __restrict__ Ws,
                                                   const float* __restrict__ dis,
                                                   ushort* __restrict__ out) {
    __shared__ ushort sB[128 * 128];
    __shared__ ushort sA[64 * 128];
    const int tid = threadIdx.x;
    const int row0 = blockIdx.x * 64;

    for (int i = tid; i < 2048; i += 256)
        ((float4*)sB)[i] = ((const float4*)Ws)[i];

    for (int i = tid; i < 2048; i += 256) {
        int m = i >> 5, u = i & 31, k4 = u << 2;
        int r = row0 + m;
        ushort4 pk = make_ushort4(0, 0, 0, 0);
        if (r < N_NODES) {
            if constexpr (sizeof(IT) == 4) {
                float4 a = ((const float4*)A)[r * 32 + u];
                pk = make_ushort4(f2h(a.x), f2h(a.y), f2h(a.z), f2h(a.w));
            } else {
                pk = ((const ushort4*)A)[r * 32 + u];
            }
        }
        *(ushort4*)&sA[swz(m, k4)] = pk;
    }
    __syncthreads();

    const int lane = tid & 63, wv = tid >> 6;
    const int mrow = lane & 15, quad = lane >> 4;
    f32x4 acc[8] = {};
#pragma unroll
    for (int kc = 0; kc < 4; ++kc) {
        int g = kc * 4 + quad;
        half8 a = *(const half8*)&sA[(wv * 16 + mrow) * 128 + ((g ^ mrow) << 3)];
#pragma unroll
        for (int nt = 0; nt < 8; ++nt) {
            half8 b = *(const half8*)&sB[(nt * 16 + mrow) * 128 + ((g ^ mrow) << 3)];
            acc[nt] = __builtin_amdgcn_mfma_f32_16x16x32_f16(a, b, acc[nt], 0, 0, 0);
        }
    }

    const int rbase = row0 + wv * 16 + quad * 4;
    float ds[4];
#pragma unroll
    for (int rg = 0; rg < 4; ++rg)
        ds[rg] = (rbase + rg < N_NODES) ? dis[rbase + rg] : 0.f;
#pragma unroll
    for (int nt = 0; nt < 8; ++nt) {
#pragma unroll
        for (int rg = 0; rg < 4; ++rg) {
            int r = rbase + rg;
            if (r < N_NODES) out[r * 128 + nt * 16 + mrow] = f2h(acc[nt][rg] * ds[rg]);
        }
    }
}

// ---------------- CSR aggregation ----------------
// out[v] = relu(dis[v] * (sum_e h'[src_e] + h'[v]) + bias), fp16 pk accumulate.
// One wave per node; half-wave per edge; 4 edges in flight per half, 2 acc pairs.

__global__ __launch_bounds__(256) void k_agg(const int* __restrict__ next,
                                             const int* __restrict__ cnt,
                                             const int* __restrict__ esrc,
                                             const ushort* __restrict__ h,
                                             const float* __restrict__ dis,
                                             const float* __restrict__ bias,
                                             ushort* __restrict__ out) {
    const int v = blockIdx.x * 4 + (threadIdx.x >> 6);
    const int lane = threadIdx.x & 63, half = lane >> 5, l = lane & 31;
    const uint2* h4 = (const uint2*)h;

    int e1 = next[v];   // == rowptr[v+1] post-scatter
    int n = cnt[v];
    const int* ep = esrc + (e1 - n);

    uint2 accA = make_uint2(0, 0), accB = make_uint2(0, 0);
    int i = half;
    for (; i + 7 < n; i += 8) {  // this half: edges i, i+2, i+4, i+6
        int s0 = ep[i], s1 = ep[i + 2], s2 = ep[i + 4], s3 = ep[i + 6];
        uint2 t0 = h4[s0 * 32 + l];
        uint2 t1 = h4[s1 * 32 + l];
        uint2 t2 = h4[s2 * 32 + l];
        uint2 t3 = h4[s3 * 32 + l];
        accA.x = pkadd(accA.x, t0.x); accA.y = pkadd(accA.y, t0.y);
        accB.x = pkadd(accB.x, t1.x); accB.y = pkadd(accB.y, t1.y);
        accA.x = pkadd(accA.x, t2.x); accA.y = pkadd(accA.y, t2.y);
        accB.x = pkadd(accB.x, t3.x); accB.y = pkadd(accB.y, t3.y);
    }
    for (; i < n; i += 2) {
        int s0 = ep[i];
        uint2 t0 = h4[s0 * 32 + l];
        accA.x = pkadd(accA.x, t0.x); accA.y = pkadd(accA.y, t0.y);
    }
    accA.x = pkadd(accA.x, accB.x);
    accA.y = pkadd(accA.y, accB.y);
    // combine halves
    accA.x = pkadd(accA.x, (uint)__shfl_xor((int)accA.x, 32));
    accA.y = pkadd(accA.y, (uint)__shfl_xor((int)accA.y, 32));

    if (half == 0) {
        uint2 hv = h4[v * 32 + l];  // self-loop term h'[v]
        accA.x = pkadd(accA.x, hv.x);
        accA.y = pkadd(accA.y, hv.y);
        float s = dis[v];
        float2 a0 = __half22float2(*(__half2*)&accA.x);
        float2 a1 = __half22float2(*(__half2*)&accA.y);
        float4 bv = *(const float4*)&bias[l * 4];
        a0.x = fmaxf(a0.x * s + bv.x, 0.f);
        a0.y = fmaxf(a0.y * s + bv.y, 0.f);
        a1.x = fmaxf(a1.x * s + bv.z, 0.f);
        a1.y = fmaxf(a1.y * s + bv.w, 0.f);
        __half2 o0 = __float22half2_rn(make_float2(a0.x, a0.y));
        __half2 o1 = __float22half2_rn(make_float2(a1.x, a1.y));
        ((uint2*)out)[v * 32 + l] = make_uint2(*(uint*)&o0, *(uint*)&o1);
    }
}

// ---------------- final MFMA: out_f32[N][64] = (x1+x2)@Wo + bo ----------------

__global__ __launch_bounds__(256) void k_final_mfma(const ushort* __restrict__ x1,
                                                    const ushort* __restrict__ x2,
                                                    const ushort* __restrict__ Ws,
                                                    const float* __restrict__ bo,
                                                    float* __restrict__ out) {
    __shared__ ushort sB[64 * 128];
    __shared__ ushort sA[64 * 128];
    const int tid = threadIdx.x;
    const int row0 = blockIdx.x * 64;

    for (int i = tid; i < 1024; i += 256)
        ((float4*)sB)[i] = ((const float4*)Ws)[i];

    for (int i = tid; i < 2048; i += 256) {
        int m = i >> 5, u = i & 31, k4 = u << 2;
        int r = row0 + m;
        uint2 pk = make_uint2(0, 0);
        if (r < N_NODES) {
            uint2 ua = ((const uint2*)x1)[r * 32 + u];
            uint2 ub = ((const uint2*)x2)[r * 32 + u];
            __half2 s0 = __hadd2(*(__half2*)&ua.x, *(__half2*)&ub.x);
            __half2 s1 = __hadd2(*(__half2*)&ua.y, *(__half2*)&ub.y);
            pk = make_uint2(*(uint*)&s0, *(uint*)&s1);
        }
        *(uint2*)&sA[swz(m, k4)] = pk;
    }
    __syncthreads();

    const int lane = tid & 63, wv = tid >> 6;
    const int mrow = lane & 15, quad = lane >> 4;
    f32x4 acc[4] = {};
#pragma unroll
    for (int kc = 0; kc < 4; ++kc) {
        int g = kc * 4 + quad;
        half8 a = *(const half8*)&sA[(wv * 16 + mrow) * 128 + ((g ^ mrow) << 3)];
#pragma unroll
        for (int nt = 0; nt < 4; ++nt) {
            half8 b = *(const half8*)&sB[(nt * 16 + mrow) * 128 + ((g ^ mrow) << 3)];
            acc[nt] = __builtin_amdgcn_mfma_f32_16x16x32_f16(a, b, acc[nt], 0, 0, 0);
        }
    }

    const int rbase = row0 + wv * 16 + quad * 4;
#pragma unroll
    for (int nt = 0; nt < 4; ++nt) {
        float bb = bo[nt * 16 + mrow];
#pragma unroll
        for (int rg = 0; rg < 4; ++rg) {
            int r = rbase + rg;
            if (r < N_NODES) out[(size_t)r * 64 + nt * 16 + mrow] = acc[nt][rg] + bb;
        }
    }
}

// ---------------- launch ----------------

extern "C" void kernel_launch(void* const* d_in, const int* in_sizes, int n_in,
                              void* d_out, int out_size, void* d_ws, size_t ws_size,
                              hipStream_t stream) {
    const float* x  = (const float*)d_in[0];
    const int*   ei = (const int*)d_in[1];
    const int*   src = ei;
    const int*   dst = ei + N_EDGES;
    const float* W1 = (const float*)d_in[2];
    const float* b1 = (const float*)d_in[3];
    const float* W2 = (const float*)d_in[4];
    const float* b2 = (const float*)d_in[5];
    const float* Wo = (const float*)d_in[6];
    const float* bo = (const float*)d_in[7];
    float* out = (float*)d_out;

    char* ws = (char*)d_ws;
    int*    cnt    = (int*)ws;            ws += 400000;
    int*    rowptr = (int*)ws;            ws += 400000;
    int*    next   = (int*)ws;            ws += 400000;
    int*    bsum   = (int*)ws;            ws += 2048;
    float*  dis    = (float*)ws;          ws += 400000;
    int*    esrc   = (int*)ws;            ws += (size_t)N_EDGES * 4;
    ushort* W1s    = (ushort*)ws;         ws += 32768;
    ushort* W2s    = (ushort*)ws;         ws += 32768;
    ushort* WoTs   = (ushort*)ws;         ws += 16384;
    ushort* h      = (ushort*)ws;         ws += (size_t)N_NODES * CH * 2;
    ushort* x1     = (ushort*)ws;         ws += (size_t)N_NODES * CH * 2;
    ushort* x2     = (ushort*)ws;

    const int B = 256;
    const int gE = (N_EDGES + B - 1) / B;
    const int gG = (N_NODES + 63) / 64;  // 1563

    // CSR build + weight prep
    hipMemsetAsync(cnt, 0, 400000, stream);
    k_count<<<(N_EDGES / 4 + B - 1) / B, B, 0, stream>>>((const int4*)dst, cnt);
    k_scan1<<<NB_SCAN, 256, 0, stream>>>(cnt, rowptr, bsum, dis);
    k_scan2<<<1, 512, 0, stream>>>(bsum);
    k_next<<<NB_SCAN, 256, 0, stream>>>(rowptr, bsum, next);
    k_scatter<<<gE, B, 0, stream>>>(src, dst, next, esrc);
    k_prepW<<<160, B, 0, stream>>>(W1, W2, Wo, W1s, W2s, WoTs);

    // layer 1
    k_gemm_mfma<float><<<gG, B, 0, stream>>>(x, W1s, dis, h);
    k_agg<<<N_NODES / 4, B, 0, stream>>>(next, cnt, esrc, h, dis, b1, x1);

    // layer 2
    k_gemm_mfma<ushort><<<gG, B, 0, stream>>>(x1, W2s, dis, h);
    k_agg<<<N_NODES / 4, B, 0, stream>>>(next, cnt, esrc, h, dis, b2, x2);

    // output projection
    k_final_mfma<<<gG, B, 0, stream>>>(x1, x2, WoTs, bo, out);
}

// Round 6
// 348.595 us; speedup vs baseline: 1.5073x; 1.4477x over previous
//
#include <hip/hip_runtime.h>
#include <hip/hip_fp16.h>

#define N_NODES 100000
#define N_EDGES 1600000
#define CH 128
#define OCH 64
#define NBUCKET 391   // ceil(100000/256) dst-buckets of 256 nodes
#define CAP 8192      // bucket capacity (mean 4092, sd ~64 -> 8192 is safe)
#define BIN_CHUNK 4096

typedef _Float16 half8 __attribute__((ext_vector_type(8)));
typedef float f32x4 __attribute__((ext_vector_type(4)));

__device__ __forceinline__ ushort f2h(float f) {
    _Float16 h = (_Float16)f;
    return *(ushort*)&h;
}

__device__ __forceinline__ uint pkadd(uint a, uint b) {
    __half2 r = __hadd2(*(__half2*)&a, *(__half2*)&b);
    return *(uint*)&r;
}

// XOR-swizzled f16 offset inside a [rows][128] f16 tile.
__device__ __forceinline__ int swz(int row, int k) {
    return row * 128 + ((((k >> 3) ^ (row & 15)) << 3) | (k & 7));
}

// ---------------- CSR build: LDS-staged counting sort ----------------
// Phase 1: bin edges by dst>>8 into 391 bucket regions, block-staged so global
// writes are contiguous runs (random 4B stores cost ~66B HBM each — r5 lesson).

__global__ __launch_bounds__(512) void k_bin(const int* __restrict__ src,
                                             const int* __restrict__ dst,
                                             int* __restrict__ bfill,
                                             int* __restrict__ bin) {
    __shared__ int hist[512];   // per-bucket count -> inclusive scan
    __shared__ int wbase[512];  // global write base minus local excl offset
    __shared__ int cur[512];    // running local cursor
    const int t = threadIdx.x;
    const int e0 = blockIdx.x * BIN_CHUNK;

    hist[t] = 0;
    __syncthreads();

    int ss[8], bb[8], dl[8];
#pragma unroll
    for (int j = 0; j < 8; ++j) {
        int e = e0 + j * 512 + t;
        bb[j] = -1;
        if (e < N_EDGES) {
            int s = src[e], d = dst[e];
            ss[j] = s; dl[j] = d & 255; bb[j] = d >> 8;
            atomicAdd(&hist[bb[j]], 1);
        }
    }
    __syncthreads();

    // Hillis-Steele inclusive scan over 512
    int v = hist[t];
    for (int off = 1; off < 512; off <<= 1) {
        int tv = (t >= off) ? hist[t - off] : 0;
        __syncthreads();
        hist[t] += tv;
        __syncthreads();
    }
    int excl = hist[t] - v;
    if (t < NBUCKET && v > 0) {
        int gb = atomicAdd(&bfill[t], v);
        wbase[t] = gb - excl;
    }
    cur[t] = excl;
    __syncthreads();

#pragma unroll
    for (int j = 0; j < 8; ++j) {
        if (bb[j] >= 0) {
            int p = atomicAdd(&cur[bb[j]], 1);
            bin[bb[j] * CAP + wbase[bb[j]] + p] = (ss[j] << 8) | dl[j];
        }
    }
}

// exclusive scan of 391 bucket counts -> bucket bases (== CSR base of node 256*b)
__global__ void k_bscan(const int* __restrict__ bfill, int* __restrict__ bbase) {
    __shared__ int tmp[512];
    int t = threadIdx.x;
    int v = (t < NBUCKET) ? bfill[t] : 0;
    tmp[t] = v;
    __syncthreads();
    for (int off = 1; off < 512; off <<= 1) {
        int tv = (t >= off) ? tmp[t - off] : 0;
        __syncthreads();
        tmp[t] += tv;
        __syncthreads();
    }
    if (t < NBUCKET) bbase[t] = tmp[t] - v;
}

// Phase 2: per bucket, per-node count+scan in LDS, reorder, stream out coalesced.
// Also emits start[], cnt[], dis[] (replaces k_count/k_scan1/k_next).
__global__ __launch_bounds__(256) void k_build(const int* __restrict__ bfill,
                                               const int* __restrict__ bbase,
                                               const int* __restrict__ bin,
                                               int* __restrict__ esrc,
                                               int* __restrict__ start,
                                               int* __restrict__ cnt,
                                               float* __restrict__ dis) {
    __shared__ int cnt_l[256];
    __shared__ int cur_l[256];
    __shared__ int sortbuf[CAP];
    const int t = threadIdx.x;
    const int b = blockIdx.x;
    const int n = bfill[b];
    const int base = bbase[b];
    const int* brec = bin + b * CAP;

    cnt_l[t] = 0;
    __syncthreads();
    for (int i = t; i < n; i += 256)
        atomicAdd(&cnt_l[brec[i] & 255], 1);
    __syncthreads();

    int v = cnt_l[t];
    for (int off = 1; off < 256; off <<= 1) {
        int tv = (t >= off) ? cnt_l[t - off] : 0;
        __syncthreads();
        cnt_l[t] += tv;
        __syncthreads();
    }
    int excl = cnt_l[t] - v;
    int node = b * 256 + t;
    if (node < N_NODES) {
        start[node] = base + excl;
        cnt[node] = v;
        dis[node] = rsqrtf((float)(v + 1));  // +1 self-loop
    }
    cur_l[t] = excl;
    __syncthreads();

    for (int i = t; i < n; i += 256) {
        int rec = brec[i];
        int p = atomicAdd(&cur_l[rec & 255], 1);
        sortbuf[p] = rec >> 8;
    }
    __syncthreads();
    for (int i = t; i < n; i += 256)
        esrc[base + i] = sortbuf[i];
}

// ---------------- weight prep (all three, one launch) ----------------

__global__ void k_prepW(const float* __restrict__ W1, const float* __restrict__ W2,
                        const float* __restrict__ Wo, ushort* __restrict__ W1s,
                        ushort* __restrict__ W2s, ushort* __restrict__ WoTs) {
    int i = blockIdx.x * blockDim.x + threadIdx.x;  // 0..40959
    if (i < 16384) {
        int k = i >> 7, n = i & 127;
        W1s[swz(n, k)] = f2h(W1[i]);
    } else if (i < 32768) {
        int j = i - 16384, k = j >> 7, n = j & 127;
        W2s[swz(n, k)] = f2h(W2[j]);
    } else if (i < 40960) {
        int j = i - 32768, k = j >> 6, n = j & 63;
        WoTs[swz(n, k)] = f2h(Wo[j]);
    }
}

// ---------------- MFMA GEMM: out_f16[r] = dis[r] * (A[r] @ W) ----------------

template <typename IT>
__global__ __launch_bounds__(256) void k_gemm_mfma(const IT* __restrict__ A,
                                                   const ushort* __restrict__ Ws,
                                                   const float* __restrict__ dis,
                                                   ushort* __restrict__ out) {
    __shared__ ushort sB[128 * 128];
    __shared__ ushort sA[64 * 128];
    const int tid = threadIdx.x;
    const int row0 = blockIdx.x * 64;

    for (int i = tid; i < 2048; i += 256)
        ((float4*)sB)[i] = ((const float4*)Ws)[i];

    for (int i = tid; i < 2048; i += 256) {
        int m = i >> 5, u = i & 31, k4 = u << 2;
        int r = row0 + m;
        ushort4 pk = make_ushort4(0, 0, 0, 0);
        if (r < N_NODES) {
            if constexpr (sizeof(IT) == 4) {
                float4 a = ((const float4*)A)[r * 32 + u];
                pk = make_ushort4(f2h(a.x), f2h(a.y), f2h(a.z), f2h(a.w));
            } else {
                pk = ((const ushort4*)A)[r * 32 + u];
            }
        }
        *(ushort4*)&sA[swz(m, k4)] = pk;
    }
    __syncthreads();

    const int lane = tid & 63, wv = tid >> 6;
    const int mrow = lane & 15, quad = lane >> 4;
    f32x4 acc[8] = {};
#pragma unroll
    for (int kc = 0; kc < 4; ++kc) {
        int g = kc * 4 + quad;
        half8 a = *(const half8*)&sA[(wv * 16 + mrow) * 128 + ((g ^ mrow) << 3)];
#pragma unroll
        for (int nt = 0; nt < 8; ++nt) {
            half8 b = *(const half8*)&sB[(nt * 16 + mrow) * 128 + ((g ^ mrow) << 3)];
            acc[nt] = __builtin_amdgcn_mfma_f32_16x16x32_f16(a, b, acc[nt], 0, 0, 0);
        }
    }

    const int rbase = row0 + wv * 16 + quad * 4;
    float ds[4];
#pragma unroll
    for (int rg = 0; rg < 4; ++rg)
        ds[rg] = (rbase + rg < N_NODES) ? dis[rbase + rg] : 0.f;
#pragma unroll
    for (int nt = 0; nt < 8; ++nt) {
#pragma unroll
        for (int rg = 0; rg < 4; ++rg) {
            int r = rbase + rg;
            if (r < N_NODES) out[r * 128 + nt * 16 + mrow] = f2h(acc[nt][rg] * ds[rg]);
        }
    }
}

// ---------------- CSR aggregation ----------------
// out[v] = relu(dis[v] * (sum_e h'[src_e] + h'[v]) + bias), fp16 pk accumulate.
// One wave per node; half-wave per edge; 4 edges in flight per half, 2 acc pairs.

__global__ __launch_bounds__(256) void k_agg(const int* __restrict__ start,
                                             const int* __restrict__ cnt,
                                             const int* __restrict__ esrc,
                                             const ushort* __restrict__ h,
                                             const float* __restrict__ dis,
                                             const float* __restrict__ bias,
                                             ushort* __restrict__ out) {
    const int v = blockIdx.x * 4 + (threadIdx.x >> 6);
    const int lane = threadIdx.x & 63, half = lane >> 5, l = lane & 31;
    const uint2* h4 = (const uint2*)h;

    int n = cnt[v];
    const int* ep = esrc + start[v];

    uint2 accA = make_uint2(0, 0), accB = make_uint2(0, 0);
    int i = half;
    for (; i + 7 < n; i += 8) {  // this half: edges i, i+2, i+4, i+6
        int s0 = ep[i], s1 = ep[i + 2], s2 = ep[i + 4], s3 = ep[i + 6];
        uint2 t0 = h4[s0 * 32 + l];
        uint2 t1 = h4[s1 * 32 + l];
        uint2 t2 = h4[s2 * 32 + l];
        uint2 t3 = h4[s3 * 32 + l];
        accA.x = pkadd(accA.x, t0.x); accA.y = pkadd(accA.y, t0.y);
        accB.x = pkadd(accB.x, t1.x); accB.y = pkadd(accB.y, t1.y);
        accA.x = pkadd(accA.x, t2.x); accA.y = pkadd(accA.y, t2.y);
        accB.x = pkadd(accB.x, t3.x); accB.y = pkadd(accB.y, t3.y);
    }
    for (; i < n; i += 2) {
        int s0 = ep[i];
        uint2 t0 = h4[s0 * 32 + l];
        accA.x = pkadd(accA.x, t0.x); accA.y = pkadd(accA.y, t0.y);
    }
    accA.x = pkadd(accA.x, accB.x);
    accA.y = pkadd(accA.y, accB.y);
    // combine halves
    accA.x = pkadd(accA.x, (uint)__shfl_xor((int)accA.x, 32));
    accA.y = pkadd(accA.y, (uint)__shfl_xor((int)accA.y, 32));

    if (half == 0) {
        uint2 hv = h4[v * 32 + l];  // self-loop term h'[v]
        accA.x = pkadd(accA.x, hv.x);
        accA.y = pkadd(accA.y, hv.y);
        float s = dis[v];
        float2 a0 = __half22float2(*(__half2*)&accA.x);
        float2 a1 = __half22float2(*(__half2*)&accA.y);
        float4 bv = *(const float4*)&bias[l * 4];
        a0.x = fmaxf(a0.x * s + bv.x, 0.f);
        a0.y = fmaxf(a0.y * s + bv.y, 0.f);
        a1.x = fmaxf(a1.x * s + bv.z, 0.f);
        a1.y = fmaxf(a1.y * s + bv.w, 0.f);
        __half2 o0 = __float22half2_rn(make_float2(a0.x, a0.y));
        __half2 o1 = __float22half2_rn(make_float2(a1.x, a1.y));
        ((uint2*)out)[v * 32 + l] = make_uint2(*(uint*)&o0, *(uint*)&o1);
    }
}

// ---------------- final MFMA: out_f32[N][64] = (x1+x2)@Wo + bo ----------------

__global__ __launch_bounds__(256) void k_final_mfma(const ushort* __restrict__ x1,
                                                    const ushort* __restrict__ x2,
                                                    const ushort* __restrict__ Ws,
                                                    const float* __restrict__ bo,
                                                    float* __restrict__ out) {
    __shared__ ushort sB[64 * 128];
    __shared__ ushort sA[64 * 128];
    const int tid = threadIdx.x;
    const int row0 = blockIdx.x * 64;

    for (int i = tid; i < 1024; i += 256)
        ((float4*)sB)[i] = ((const float4*)Ws)[i];

    for (int i = tid; i < 2048; i += 256) {
        int m = i >> 5, u = i & 31, k4 = u << 2;
        int r = row0 + m;
        uint2 pk = make_uint2(0, 0);
        if (r < N_NODES) {
            uint2 ua = ((const uint2*)x1)[r * 32 + u];
            uint2 ub = ((const uint2*)x2)[r * 32 + u];
            __half2 s0 = __hadd2(*(__half2*)&ua.x, *(__half2*)&ub.x);
            __half2 s1 = __hadd2(*(__half2*)&ua.y, *(__half2*)&ub.y);
            pk = make_uint2(*(uint*)&s0, *(uint*)&s1);
        }
        *(uint2*)&sA[swz(m, k4)] = pk;
    }
    __syncthreads();

    const int lane = tid & 63, wv = tid >> 6;
    const int mrow = lane & 15, quad = lane >> 4;
    f32x4 acc[4] = {};
#pragma unroll
    for (int kc = 0; kc < 4; ++kc) {
        int g = kc * 4 + quad;
        half8 a = *(const half8*)&sA[(wv * 16 + mrow) * 128 + ((g ^ mrow) << 3)];
#pragma unroll
        for (int nt = 0; nt < 4; ++nt) {
            half8 b = *(const half8*)&sB[(nt * 16 + mrow) * 128 + ((g ^ mrow) << 3)];
            acc[nt] = __builtin_amdgcn_mfma_f32_16x16x32_f16(a, b, acc[nt], 0, 0, 0);
        }
    }

    const int rbase = row0 + wv * 16 + quad * 4;
#pragma unroll
    for (int nt = 0; nt < 4; ++nt) {
        float bb = bo[nt * 16 + mrow];
#pragma unroll
        for (int rg = 0; rg < 4; ++rg) {
            int r = rbase + rg;
            if (r < N_NODES) out[(size_t)r * 64 + nt * 16 + mrow] = acc[nt][rg] + bb;
        }
    }
}

// ---------------- launch ----------------

extern "C" void kernel_launch(void* const* d_in, const int* in_sizes, int n_in,
                              void* d_out, int out_size, void* d_ws, size_t ws_size,
                              hipStream_t stream) {
    const float* x  = (const float*)d_in[0];
    const int*   ei = (const int*)d_in[1];
    const int*   src = ei;
    const int*   dst = ei + N_EDGES;
    const float* W1 = (const float*)d_in[2];
    const float* b1 = (const float*)d_in[3];
    const float* W2 = (const float*)d_in[4];
    const float* b2 = (const float*)d_in[5];
    const float* Wo = (const float*)d_in[6];
    const float* bo = (const float*)d_in[7];
    float* out = (float*)d_out;

    char* ws = (char*)d_ws;
    int*    bfill  = (int*)ws;            ws += 2048;
    int*    bbase  = (int*)ws;            ws += 2048;
    int*    cnt    = (int*)ws;            ws += 400000;
    int*    start  = (int*)ws;            ws += 400000;
    float*  dis    = (float*)ws;          ws += 400000;  // 16B-aligned offsets
    int*    bin    = (int*)ws;            ws += (size_t)NBUCKET * CAP * 4;
    int*    esrc   = (int*)ws;            ws += (size_t)N_EDGES * 4;
    ushort* W1s    = (ushort*)ws;         ws += 32768;
    ushort* W2s    = (ushort*)ws;         ws += 32768;
    ushort* WoTs   = (ushort*)ws;         ws += 16384;
    ushort* h      = (ushort*)ws;         ws += (size_t)N_NODES * CH * 2;
    ushort* x1     = (ushort*)ws;         ws += (size_t)N_NODES * CH * 2;
    ushort* x2     = (ushort*)ws;

    const int B = 256;
    const int gG = (N_NODES + 63) / 64;  // 1563

    // CSR build (LDS-staged counting sort) + weight prep
    hipMemsetAsync(bfill, 0, 2048, stream);
    k_bin<<<(N_EDGES + BIN_CHUNK - 1) / BIN_CHUNK, 512, 0, stream>>>(src, dst, bfill, bin);
    k_bscan<<<1, 512, 0, stream>>>(bfill, bbase);
    k_build<<<NBUCKET, 256, 0, stream>>>(bfill, bbase, bin, esrc, start, cnt, dis);
    k_prepW<<<160, B, 0, stream>>>(W1, W2, Wo, W1s, W2s, WoTs);

    // layer 1
    k_gemm_mfma<float><<<gG, B, 0, stream>>>(x, W1s, dis, h);
    k_agg<<<N_NODES / 4, B, 0, stream>>>(start, cnt, esrc, h, dis, b1, x1);

    // layer 2
    k_gemm_mfma<ushort><<<gG, B, 0, stream>>>(x1, W2s, dis, h);
    k_agg<<<N_NODES / 4, B, 0, stream>>>(start, cnt, esrc, h, dis, b2, x2);

    // output projection
    k_final_mfma<<<gG, B, 0, stream>>>(x1, x2, WoTs, bo, out);
}